// Round 6
// baseline (276.999 us; speedup 1.0000x reference)
//
#include <hip/hip_runtime.h>
#include <hip/hip_fp16.h>

typedef _Float16 f16x8 __attribute__((ext_vector_type(8)));
typedef float float4v __attribute__((ext_vector_type(4)));
typedef __attribute__((ext_vector_type(8))) short short8;
typedef __attribute__((ext_vector_type(16))) float f32x16;

// workspace layout (float offsets)
#define WS_BFH   0          // 65536 halfs: apw in MFMA B-frag fp16 layout
#define WS_BSG   65536      // 2*256 sigmoid(B_s)[hn]
#define WS_OUTS  66048      // 2*1024*256 outs[d][l][hn]
#define WS_KC    590336     // 32*63*64 Kcomb[c][U][V] (V=63 zero pad)
#define WS_XPAD  719360     // 256*126*64 halfs: x bf16, 31-row zero pad top/bot
#define WS_YC    1767936    // 8*32*64*64 conv result [b][c][p][q] fp32
#define WS_TF    2816512    // 2016*8*512 halfs: Toeplitz T in B-frag bf16 layout

#define AROW 260            // LDS row stride (floats): 4 mats * 64 + 4 pad

__device__ inline unsigned short f2bf(float f) {
  unsigned int u = __float_as_uint(f);
  u += 0x7fffu + ((u >> 16) & 1u);
  return (unsigned short)(u >> 16);
}

__device__ __forceinline__ void gl_lds16(const void* g, void* l) {
  __builtin_amdgcn_global_load_lds((const __attribute__((address_space(1))) void*)g,
                                   (__attribute__((address_space(3))) void*)l, 16, 0, 0);
}

// ---------------- K0: sigmoid powers -> fp16 B-fragment layout ----------------
__global__ void k0_prep(const float* __restrict__ A1, const float* __restrict__ A2,
                        const float* __restrict__ A3, const float* __restrict__ A4,
                        const float* __restrict__ B1, const float* __restrict__ B2,
                        _Float16* __restrict__ Bfh, float* __restrict__ bsg) {
  const int blk = blockIdx.x;        // 0..7 = i*2 + kb
  const int i = blk >> 1, kb = blk & 1;
  const int hn = threadIdx.x;        // 0..255
  const float* As[4] = {A1, A2, A3, A4};
  const float a = As[i][hn];
  const float s = 1.0f / (1.0f + expf(-a));
  float p = 1.0f;
  for (int v = 0; v < kb * 32; ++v) p *= s;
  const int ntile = hn >> 4;
  #pragma unroll
  for (int g = 0; g < 4; ++g) {
    _Float16 h[8];
    #pragma unroll
    for (int j = 0; j < 8; ++j) { h[j] = (_Float16)p; p *= s; }
    const int lane = (hn & 15) | (g << 4);
    _Float16* dst = Bfh + ((((i * 2 + kb) * 16 + ntile) * 64 + lane) << 3);
    *(f16x8*)dst = *(f16x8*)h;
  }
  if (blk == 0) {
    bsg[hn]       = 1.0f / (1.0f + expf(-B1[hn]));
    bsg[256 + hn] = 1.0f / (1.0f + expf(-B2[hn]));
  }
}

// ---------------- K1: persistent double-buffered MFMA pipeline ----------------
// 256 blocks, 1/CU. Each handles 8 (d,l) tiles: gi = blockIdx + k*256.
// M staged fp32 -> LDS via global_load_lds (async); B-frags in 128 regs.
__global__ __launch_bounds__(256, 1) void k1_mfma(
    const float* __restrict__ Mh0, const float* __restrict__ Mh1,
    const float* __restrict__ Mh2, const float* __restrict__ Mh3,
    const float* __restrict__ MhB,
    const float* __restrict__ Mv0, const float* __restrict__ Mv1,
    const float* __restrict__ Mv2, const float* __restrict__ Mv3,
    const float* __restrict__ MvB,
    const _Float16* __restrict__ Bfh, const float* __restrict__ bsg,
    float* __restrict__ outs) {
  __shared__ __align__(16) float Abuf[2][64 * AROW + 128];  // + MB 128 floats
  __shared__ float bsgs[512];

  const int t = threadIdx.x;
  const int w = t >> 6, lane = t & 63;
  const int g = lane >> 4, cc = lane & 15;   // g: mat (stage) / k-group (frag)

  bsgs[t]       = bsg[t];
  bsgs[256 + t] = bsg[256 + t];

  // B-frag preload (once per block): Bf[i][kb][n], 128 VGPRs
  f16x8 Bf[4][2][4];
  #pragma unroll
  for (int i = 0; i < 4; ++i)
    #pragma unroll
    for (int kb = 0; kb < 2; ++kb)
      #pragma unroll
      for (int n = 0; n < 4; ++n)
        Bf[i][kb][n] = *(const f16x8*)(Bfh +
            ((((i * 2 + kb) * 16 + (w * 4 + n)) * 64 + lane) << 3));

  // async stage of tile gi into Abuf[buf]
  auto stage = [&](int buf, int gi) {
    const int bd = gi >> 10, l = gi & 1023;
    const float* M0 = bd ? Mv0 : Mh0;
    const float* M1 = bd ? Mv1 : Mh1;
    const float* M2 = bd ? Mv2 : Mh2;
    const float* M3 = bd ? Mv3 : Mh3;
    const float* mp = (g == 0) ? M0 : (g == 1) ? M1 : (g == 2) ? M2 : M3;
    const float* gp = mp + (size_t)(l * 64) * 64 + cc * 4;  // per-lane
    float* lb = &Abuf[buf][0];
    #pragma unroll
    for (int it = 0; it < 16; ++it) {
      const int r = w * 16 + it;
      gl_lds16(gp + r * 64, lb + r * AROW);
    }
    if (w == 0 && lane < 32) {
      const float* MBp = bd ? MvB : MhB;
      gl_lds16(MBp + l * 128 + lane * 4, lb + 64 * AROW);
    }
  };

  stage(0, blockIdx.x);

  for (int k = 0; k < 8; ++k) {
    __syncthreads();                       // drains stage(k) (vmcnt before barrier)
    if (k < 7) stage((k + 1) & 1, blockIdx.x + ((k + 1) << 8));

    const int gi = blockIdx.x + (k << 8);
    const int bd = gi >> 10, l = gi & 1023;
    const float* Ap = &Abuf[k & 1][0];

    float4v E[4][4];
    #pragma unroll
    for (int i = 0; i < 4; ++i) {
      float4v acc[4][4];
      #pragma unroll
      for (int m = 0; m < 4; ++m)
        #pragma unroll
        for (int n = 0; n < 4; ++n) acc[m][n] = (float4v){0.f, 0.f, 0.f, 0.f};
      #pragma unroll
      for (int kb = 0; kb < 2; ++kb)
        #pragma unroll
        for (int m = 0; m < 4; ++m) {
          const float* ar = Ap + (m * 16 + cc) * AROW + i * 64 + kb * 32 + g * 8;
          const float4 f0 = *(const float4*)ar;
          const float4 f1 = *(const float4*)(ar + 4);
          const f16x8 Af = {(_Float16)f0.x, (_Float16)f0.y, (_Float16)f0.z, (_Float16)f0.w,
                            (_Float16)f1.x, (_Float16)f1.y, (_Float16)f1.z, (_Float16)f1.w};
          #pragma unroll
          for (int n = 0; n < 4; ++n)
            acc[m][n] = __builtin_amdgcn_mfma_f32_16x16x32_f16(Af, Bf[i][kb][n], acc[m][n], 0, 0, 0);
        }
      if (i == 0) {
        #pragma unroll
        for (int m = 0; m < 4; ++m)
          #pragma unroll
          for (int n = 0; n < 4; ++n) E[m][n] = acc[m][n];
      } else {
        #pragma unroll
        for (int m = 0; m < 4; ++m)
          #pragma unroll
          for (int n = 0; n < 4; ++n) E[m][n] *= acc[m][n];
      }
    }

    // epilogue: * Bdot, reduce over 64 rows, write outs[d][l][hn]
    const float* MBl = Ap + 64 * AROW;
    float2 mb[16];
    #pragma unroll
    for (int m = 0; m < 4; ++m)
      #pragma unroll
      for (int r = 0; r < 4; ++r)
        mb[m * 4 + r] = *(const float2*)(MBl + (m * 16 + g * 4 + r) * 2);

    #pragma unroll
    for (int n = 0; n < 4; ++n) {
      const int hn = w * 64 + n * 16 + cc;
      const float b0 = bsgs[hn], b1 = bsgs[256 + hn];
      float ssum = 0.f;
      #pragma unroll
      for (int m = 0; m < 4; ++m)
        #pragma unroll
        for (int r = 0; r < 4; ++r)
          ssum = fmaf(E[m][n][r], mb[m * 4 + r].x * b0 + mb[m * 4 + r].y * b1, ssum);
      ssum += __shfl_xor(ssum, 16);
      ssum += __shfl_xor(ssum, 32);
      if (lane < 16) outs[(bd * 1024 + l) * 256 + hn] = ssum;
    }
  }
}

// ---------------- K2: build combined 63x63 kernel (256 blocks) ----------------
__global__ void k2_kc(const float* __restrict__ outs, const float* __restrict__ C1,
                      const float* __restrict__ C2, float* __restrict__ kc) {
  const int c = blockIdx.x >> 3;
  const int base = (blockIdx.x & 7) * 504;
  const float SC = 0.70710678118654752f;
  for (int idx = base + threadIdx.x; idx < base + 504 && idx < 63 * 64; idx += 256) {
    const int U = idx >> 6, V = idx & 63;
    float acc = 0.f;
    if (V < 63) {
      const int u = U - 31, v = V - 31;
      #pragma unroll
      for (int d = 0; d < 4; ++d) {
        const int dy = (d == 1 || d == 3) ? u : -u;
        const int dx = (d == 2 || d == 3) ? v : -v;
        if (dy >= 0 && dy < 32 && dx >= 0 && dx < 32) {
          const int l = dy * 32 + dx;
          const int h = d * 32 + c;
          const float e = (dy == 0 && dx == 0) ? 1.f : ((dy == 0 || dx == 0) ? 2.f : 1.f);
          const float s0 = outs[l * 256 + h * 2 + 0] * C1[h * 2 + 0]
                         + outs[l * 256 + h * 2 + 1] * C1[h * 2 + 1];
          const float s1 = outs[262144 + l * 256 + h * 2 + 0] * C2[h * 2 + 0]
                         + outs[262144 + l * 256 + h * 2 + 1] * C2[h * 2 + 1];
          acc += e * SC * (s0 + s1);
        }
      }
    }
    kc[(c * 63 + U) * 64 + V] = acc;
  }
}

// ---------------- K2b: kc -> Toeplitz T in bf16 B-frag layout ----------------
// B[k][n] = T_u[k][n] = kc[c][u][k-n+31] (0 outside band); k = input column.
__global__ void k2b_tfrag(const float* __restrict__ kc, unsigned short* __restrict__ Tf) {
  const int cu = blockIdx.x;          // c*63+u
  const float* kcr = kc + cu * 64;
  const int t = threadIdx.x;
  #pragma unroll
  for (int s = 0; s < 2; ++s) {
    const int slot = t + s * 256;     // 0..511
    const int f = slot >> 6, lane = slot & 63;
    const int kt = f >> 1, nt = f & 1;
    const int kbase = kt * 16 + (lane >> 5) * 8;
    const int n = nt * 32 + (lane & 31);
    unsigned int o[4];
    #pragma unroll
    for (int jp = 0; jp < 4; ++jp) {
      unsigned short h0, h1;
      {
        const int v = (kbase + 2 * jp) - n + 31;
        h0 = (v >= 0 && v < 63) ? f2bf(kcr[v]) : 0;
      }
      {
        const int v = (kbase + 2 * jp + 1) - n + 31;
        h1 = (v >= 0 && v < 63) ? f2bf(kcr[v]) : 0;
      }
      o[jp] = (unsigned int)h0 | ((unsigned int)h1 << 16);
    }
    unsigned int* dst = (unsigned int*)(Tf + (cu * 8 + f) * 512 + lane * 8);
    dst[0] = o[0]; dst[1] = o[1]; dst[2] = o[2]; dst[3] = o[3];
  }
}

// ---------------- K3: transpose x (b,p,q,c) -> bf16 padded [bc][p+31][q] ----------------
__global__ void k3_xt(const float* __restrict__ x, unsigned short* __restrict__ Xpad) {
  __shared__ float ls[4 * 64 * 33];
  const int b = blockIdx.x >> 4, pt = blockIdx.x & 15;
  const int t = threadIdx.x;
  const float* src = x + (b * 64 + pt * 4) * 2048;
  #pragma unroll 8
  for (int k = 0; k < 32; ++k) {
    const int e = t + k * 256;                        // 0..8191
    const int p = e >> 11, q = (e >> 5) & 63, cl = e & 31;
    ls[(p * 64 + q) * 33 + cl] = src[e];
  }
  unsigned int* Xp32 = (unsigned int*)Xpad;
  if (pt == 0) {
    for (int idx = t; idx < 31744; idx += 256) {     // rows 0..30
      const int c = idx / 992, r = idx - c * 992;
      Xp32[(b * 32 + c) * 4032 + r] = 0u;
    }
  }
  if (pt == 15) {
    for (int idx = t; idx < 31744; idx += 256) {     // rows 95..125
      const int c = idx / 992, r = idx - c * 992;
      Xp32[(b * 32 + c) * 4032 + 3040 + r] = 0u;
    }
  }
  __syncthreads();
  #pragma unroll 8
  for (int k = 0; k < 16; ++k) {
    const int o = t + k * 256;                        // 0..4095 q-pairs
    const int cl = o >> 7, p = (o >> 5) & 3, q2 = o & 31;
    const float f0 = ls[(p * 64 + 2 * q2 + 0) * 33 + cl];
    const float f1 = ls[(p * 64 + 2 * q2 + 1) * 33 + cl];
    const unsigned int pk = (unsigned int)f2bf(f0) | ((unsigned int)f2bf(f1) << 16);
    Xp32[(b * 32 + cl) * 4032 + (pt * 4 + p + 31) * 32 + q2] = pk;
  }
}

// ---------------- K4b: conv as sum of 63 Toeplitz GEMMs (MFMA bf16) ----------------
__global__ __launch_bounds__(256, 1) void k4b_conv(const unsigned short* __restrict__ Xpad,
                                                   const unsigned short* __restrict__ Tf,
                                                   float* __restrict__ yc) {
  __shared__ float red[4 * 4096];
  const int bc = blockIdx.x;
  const int c  = bc & 31;
  const int t = threadIdx.x, w = t >> 6, lane = t & 63;
  const unsigned short* Xp = Xpad + bc * 8064;
  const unsigned short* Tc = Tf + c * 63 * 4096;
  const int r = lane & 31, kh = lane >> 5;

  f32x16 acc[2][2];
  #pragma unroll
  for (int m = 0; m < 2; ++m)
    #pragma unroll
    for (int n = 0; n < 2; ++n)
      #pragma unroll
      for (int e = 0; e < 16; ++e) acc[m][n][e] = 0.f;

  short8 Ac[2][4], Bc[4][2];
  int u = w;
  #pragma unroll
  for (int m = 0; m < 2; ++m)
    #pragma unroll
    for (int kt = 0; kt < 4; ++kt)
      Ac[m][kt] = *(const short8*)(Xp + (m * 32 + r + u) * 64 + kt * 16 + kh * 8);
  #pragma unroll
  for (int kt = 0; kt < 4; ++kt)
    #pragma unroll
    for (int nt = 0; nt < 2; ++nt)
      Bc[kt][nt] = *(const short8*)(Tc + (u * 8 + kt * 2 + nt) * 512 + lane * 8);

  for (int i = 0; i < 16; ++i) {
    const int un = u + 4;
    const bool has_next = (un < 63);
    short8 An[2][4], Bn[4][2];
    if (has_next) {
      #pragma unroll
      for (int m = 0; m < 2; ++m)
        #pragma unroll
        for (int kt = 0; kt < 4; ++kt)
          An[m][kt] = *(const short8*)(Xp + (m * 32 + r + un) * 64 + kt * 16 + kh * 8);
      #pragma unroll
      for (int kt = 0; kt < 4; ++kt)
        #pragma unroll
        for (int nt = 0; nt < 2; ++nt)
          Bn[kt][nt] = *(const short8*)(Tc + (un * 8 + kt * 2 + nt) * 512 + lane * 8);
    }
    #pragma unroll
    for (int kt = 0; kt < 4; ++kt)
      #pragma unroll
      for (int m = 0; m < 2; ++m)
        #pragma unroll
        for (int nt = 0; nt < 2; ++nt)
          acc[m][nt] = __builtin_amdgcn_mfma_f32_32x32x16_bf16(Ac[m][kt], Bc[kt][nt],
                                                               acc[m][nt], 0, 0, 0);
    if (!has_next) break;
    #pragma unroll
    for (int m = 0; m < 2; ++m)
      #pragma unroll
      for (int kt = 0; kt < 4; ++kt) Ac[m][kt] = An[m][kt];
    #pragma unroll
    for (int kt = 0; kt < 4; ++kt)
      #pragma unroll
      for (int nt = 0; nt < 2; ++nt) Bc[kt][nt] = Bn[kt][nt];
    u = un;
  }

  float* my = red + w * 4096;
  #pragma unroll
  for (int m = 0; m < 2; ++m)
    #pragma unroll
    for (int nt = 0; nt < 2; ++nt)
      #pragma unroll
      for (int e = 0; e < 16; ++e) {
        const int row = (e & 3) + 8 * (e >> 2) + 4 * kh;
        my[(m * 32 + row) * 64 + nt * 32 + r] = acc[m][nt][e];
      }
  __syncthreads();
  float* out = yc + bc * 4096;
  #pragma unroll
  for (int k = 0; k < 16; ++k) {
    const int idx = t + k * 256;
    out[idx] = red[idx] + red[4096 + idx] + red[8192 + idx] + red[12288 + idx];
  }
}

// ---------------- K5: channel mix y @ W^T + b ----------------
__global__ void k5_out(const float* __restrict__ yc, const float* __restrict__ W,
                       const float* __restrict__ bias, float* __restrict__ out) {
  __shared__ float ysh[64 * 33];
  const int b = blockIdx.x >> 6, p = blockIdx.x & 63;
  const int t = threadIdx.x;
  const float* ybp = yc + b * 131072 + p * 64;
  #pragma unroll
  for (int k = 0; k < 8; ++k) {
    const int f = t + k * 256;
    const int cch = f >> 6, q = f & 63;
    ysh[q * 33 + cch] = ybp[cch * 4096 + q];
  }
  const int e = t & 31;
  float wr[32];
  #pragma unroll
  for (int c4 = 0; c4 < 8; ++c4) {
    const float4 f4 = *(const float4*)(W + e * 32 + c4 * 4);
    wr[c4 * 4 + 0] = f4.x; wr[c4 * 4 + 1] = f4.y;
    wr[c4 * 4 + 2] = f4.z; wr[c4 * 4 + 3] = f4.w;
  }
  const float bb = bias[e];
  __syncthreads();
  const int q0 = t >> 5;
  #pragma unroll
  for (int k = 0; k < 8; ++k) {
    const int q = q0 + k * 8;
    float a = bb;
    #pragma unroll
    for (int cc = 0; cc < 32; ++cc) a = fmaf(ysh[q * 33 + cc], wr[cc], a);
    out[((b * 64 + p) * 64 + q) * 32 + e] = a;
  }
}

extern "C" void kernel_launch(void* const* d_in, const int* in_sizes, int n_in,
                              void* d_out, int out_size, void* d_ws, size_t ws_size,
                              hipStream_t stream) {
  const float* x   = (const float*)d_in[0];
  const float* Mh[5] = {(const float*)d_in[1], (const float*)d_in[2], (const float*)d_in[3],
                        (const float*)d_in[4], (const float*)d_in[5]};
  const float* Mv[5] = {(const float*)d_in[6], (const float*)d_in[7], (const float*)d_in[8],
                        (const float*)d_in[9], (const float*)d_in[10]};
  const float* A1 = (const float*)d_in[11];
  const float* A2 = (const float*)d_in[12];
  const float* A3 = (const float*)d_in[13];
  const float* A4 = (const float*)d_in[14];
  const float* B1 = (const float*)d_in[15];
  const float* B2 = (const float*)d_in[16];
  const float* C1 = (const float*)d_in[17];
  const float* C2 = (const float*)d_in[18];
  const float* W  = (const float*)d_in[19];
  const float* bb = (const float*)d_in[20];
  float* ws  = (float*)d_ws;
  _Float16* Bfh = (_Float16*)(ws + WS_BFH);
  float* bsg  = ws + WS_BSG;
  float* outs = ws + WS_OUTS;
  float* kc   = ws + WS_KC;
  unsigned short* Xpad = (unsigned short*)(ws + WS_XPAD);
  float* yc   = ws + WS_YC;
  unsigned short* Tf = (unsigned short*)(ws + WS_TF);

  k0_prep<<<8, 256, 0, stream>>>(A1, A2, A3, A4, B1, B2, Bfh, bsg);
  k3_xt<<<128, 256, 0, stream>>>(x, Xpad);
  k1_mfma<<<256, 256, 0, stream>>>(Mh[0], Mh[1], Mh[2], Mh[3], Mh[4],
                                   Mv[0], Mv[1], Mv[2], Mv[3], Mv[4],
                                   Bfh, bsg, outs);
  k2_kc<<<256, 256, 0, stream>>>(outs, C1, C2, kc);
  k2b_tfrag<<<2016, 256, 0, stream>>>(kc, Tf);
  k4b_conv<<<256, 256, 0, stream>>>(Xpad, Tf, yc);
  k5_out<<<512, 256, 0, stream>>>(yc, W, bb, (float*)d_out);
}

// Round 7
// 253.672 us; speedup vs baseline: 1.0920x; 1.0920x over previous
//
#include <hip/hip_runtime.h>
#include <hip/hip_fp16.h>

typedef _Float16 f16x8 __attribute__((ext_vector_type(8)));
typedef _Float16 half4v __attribute__((ext_vector_type(4)));
typedef float float4v __attribute__((ext_vector_type(4)));
typedef __attribute__((ext_vector_type(8))) short short8;
typedef __attribute__((ext_vector_type(16))) float f32x16;

// workspace layout (float offsets)
#define WS_BFH   0          // 65536 halfs: apw in MFMA B-frag fp16 layout
#define WS_BSG   65536      // 2*256 sigmoid(B_s)[hn]
#define WS_OUTS  66048      // 2*1024*256 outs[d][l][hn]
#define WS_KC    590336     // 32*63*64 Kcomb[c][U][V] (V=63 zero pad)
#define WS_XPAD  719360     // 256*126*64 halfs: x bf16, 31-row zero pad top/bot
#define WS_YC    1767936    // 8*32*64*64 conv result [b][c][p][q] fp32
#define WS_TF    2816512    // 2016*8*512 halfs: Toeplitz T in B-frag bf16 layout

__device__ inline unsigned short f2bf(float f) {
  unsigned int u = __float_as_uint(f);
  u += 0x7fffu + ((u >> 16) & 1u);
  return (unsigned short)(u >> 16);
}

// ---------------- K0: sigmoid powers -> fp16 B-fragment layout ----------------
__global__ void k0_prep(const float* __restrict__ A1, const float* __restrict__ A2,
                        const float* __restrict__ A3, const float* __restrict__ A4,
                        const float* __restrict__ B1, const float* __restrict__ B2,
                        _Float16* __restrict__ Bfh, float* __restrict__ bsg) {
  const int blk = blockIdx.x;        // 0..7 = i*2 + kb
  const int i = blk >> 1, kb = blk & 1;
  const int hn = threadIdx.x;        // 0..255
  const float* As[4] = {A1, A2, A3, A4};
  const float a = As[i][hn];
  const float s = 1.0f / (1.0f + expf(-a));
  float p = 1.0f;
  for (int v = 0; v < kb * 32; ++v) p *= s;
  const int ntile = hn >> 4;
  #pragma unroll
  for (int g = 0; g < 4; ++g) {
    _Float16 h[8];
    #pragma unroll
    for (int j = 0; j < 8; ++j) { h[j] = (_Float16)p; p *= s; }
    const int lane = (hn & 15) | (g << 4);
    _Float16* dst = Bfh + ((((i * 2 + kb) * 16 + ntile) * 64 + lane) << 3);
    *(f16x8*)dst = *(f16x8*)h;
  }
  if (blk == 0) {
    bsg[hn]       = 1.0f / (1.0f + expf(-B1[hn]));
    bsg[256 + hn] = 1.0f / (1.0f + expf(-B2[hn]));
  }
}

// ---------------- K1: SSM kernel contraction via MFMA ----------------
// Round-5 structure (4 blocks/CU) + burst staging: all 16 global float4 loads
// issued before any cvt/ds_write -> one HBM latency per block, not four.
__global__ __launch_bounds__(256, 4) void k1_mfma(
    const float* __restrict__ Mh0, const float* __restrict__ Mh1,
    const float* __restrict__ Mh2, const float* __restrict__ Mh3,
    const float* __restrict__ MhB,
    const float* __restrict__ Mv0, const float* __restrict__ Mv1,
    const float* __restrict__ Mv2, const float* __restrict__ Mv3,
    const float* __restrict__ MvB,
    const _Float16* __restrict__ Bfh, const float* __restrict__ bsg,
    float* __restrict__ outs) {
  __shared__ _Float16 Alds[4 * 4 * 2 * 64 * 8];  // [i][m][kb][lane][j] = 32 KB
  __shared__ float MBs[128];
  __shared__ float bsgs[512];

  const int bd = blockIdx.x >> 10;
  const int l  = blockIdx.x & 1023;
  const float* Ms[4] = {bd ? Mv0 : Mh0, bd ? Mv1 : Mh1, bd ? Mv2 : Mh2, bd ? Mv3 : Mh3};
  const float* MB    = bd ? MvB : MhB;
  const int t = threadIdx.x;

  if (t < 128) MBs[t] = MB[l * 128 + t];
  bsgs[t]       = bsg[t];
  bsgs[256 + t] = bsg[256 + t];

  // ---- burst stage: issue ALL 16 loads, then cvt+store ----
  float4 st[16];
  #pragma unroll
  for (int i = 0; i < 4; ++i) {
    const float* M = Ms[i] + l * 4096;
    #pragma unroll
    for (int c0 = 0; c0 < 4; ++c0) {
      const int c = t + c0 * 256;
      st[i * 4 + c0] = *(const float4*)(M + ((c >> 4) * 64) + ((c & 15) << 2));
    }
  }
  #pragma unroll
  for (int i = 0; i < 4; ++i)
    #pragma unroll
    for (int c0 = 0; c0 < 4; ++c0) {
      const int c = t + c0 * 256;
      const int row = c >> 4;
      const int v4  = (c & 15) << 2;
      const int m     = row >> 4;
      const int lane2 = (row & 15) | (((v4 >> 3) & 3) << 4);
      const int kb    = v4 >> 5;
      const int jj    = v4 & 7;
      const float4 f = st[i * 4 + c0];
      half4v* dst = (half4v*)&Alds[((((i * 4 + m) * 2 + kb) * 64 + lane2) << 3) + jj];
      *dst = (half4v){(_Float16)f.x, (_Float16)f.y, (_Float16)f.z, (_Float16)f.w};
    }
  __syncthreads();

  const int w    = t >> 6;
  const int lane = t & 63;
  const int q = lane >> 4, col = lane & 15;

  #pragma unroll
  for (int half = 0; half < 2; ++half) {
    float4v E[4][2];
    #pragma unroll
    for (int i = 0; i < 4; ++i) {
      float4v acc[4][2];
      #pragma unroll
      for (int m = 0; m < 4; ++m)
        #pragma unroll
        for (int n = 0; n < 2; ++n) acc[m][n] = (float4v){0.f, 0.f, 0.f, 0.f};
      f16x8 Bf[2][2];
      #pragma unroll
      for (int kb = 0; kb < 2; ++kb)
        #pragma unroll
        for (int n = 0; n < 2; ++n)
          Bf[kb][n] = *(const f16x8*)(Bfh +
              ((((i * 2 + kb) * 16 + (w * 4 + half * 2 + n)) * 64 + lane) << 3));
      #pragma unroll
      for (int kb = 0; kb < 2; ++kb)
        #pragma unroll
        for (int m = 0; m < 4; ++m) {
          const f16x8 Af = *(const f16x8*)&Alds[((((i * 4 + m) * 2 + kb) * 64 + lane) << 3)];
          #pragma unroll
          for (int n = 0; n < 2; ++n)
            acc[m][n] = __builtin_amdgcn_mfma_f32_16x16x32_f16(Af, Bf[kb][n], acc[m][n], 0, 0, 0);
        }
      if (i == 0) {
        #pragma unroll
        for (int m = 0; m < 4; ++m)
          #pragma unroll
          for (int n = 0; n < 2; ++n) E[m][n] = acc[m][n];
      } else {
        #pragma unroll
        for (int m = 0; m < 4; ++m)
          #pragma unroll
          for (int n = 0; n < 2; ++n) E[m][n] *= acc[m][n];
      }
    }

    #pragma unroll
    for (int n = 0; n < 2; ++n) {
      const int hn = w * 64 + (half * 2 + n) * 16 + col;
      const float b0 = bsgs[hn], b1 = bsgs[256 + hn];
      float ssum = 0.f;
      #pragma unroll
      for (int m = 0; m < 4; ++m)
        #pragma unroll
        for (int r = 0; r < 4; ++r) {
          const int row = m * 16 + q * 4 + r;
          const float bdot = MBs[row * 2] * b0 + MBs[row * 2 + 1] * b1;
          ssum = fmaf(E[m][n][r], bdot, ssum);
        }
      ssum += __shfl_xor(ssum, 16);
      ssum += __shfl_xor(ssum, 32);
      if (lane < 16) outs[(bd * 1024 + l) * 256 + hn] = ssum;
    }
  }
}

// ---------------- K2: build combined 63x63 kernel (256 blocks) ----------------
__global__ void k2_kc(const float* __restrict__ outs, const float* __restrict__ C1,
                      const float* __restrict__ C2, float* __restrict__ kc) {
  const int c = blockIdx.x >> 3;
  const int base = (blockIdx.x & 7) * 504;
  const float SC = 0.70710678118654752f;
  for (int idx = base + threadIdx.x; idx < base + 504 && idx < 63 * 64; idx += 256) {
    const int U = idx >> 6, V = idx & 63;
    float acc = 0.f;
    if (V < 63) {
      const int u = U - 31, v = V - 31;
      #pragma unroll
      for (int d = 0; d < 4; ++d) {
        const int dy = (d == 1 || d == 3) ? u : -u;
        const int dx = (d == 2 || d == 3) ? v : -v;
        if (dy >= 0 && dy < 32 && dx >= 0 && dx < 32) {
          const int l = dy * 32 + dx;
          const int h = d * 32 + c;
          const float e = (dy == 0 && dx == 0) ? 1.f : ((dy == 0 || dx == 0) ? 2.f : 1.f);
          const float s0 = outs[l * 256 + h * 2 + 0] * C1[h * 2 + 0]
                         + outs[l * 256 + h * 2 + 1] * C1[h * 2 + 1];
          const float s1 = outs[262144 + l * 256 + h * 2 + 0] * C2[h * 2 + 0]
                         + outs[262144 + l * 256 + h * 2 + 1] * C2[h * 2 + 1];
          acc += e * SC * (s0 + s1);
        }
      }
    }
    kc[(c * 63 + U) * 64 + V] = acc;
  }
}

// ---------------- K2b: kc -> Toeplitz T in bf16 B-frag layout ----------------
// B[k][n] = T_u[k][n] = kc[c][u][k-n+31] (0 outside band); k = input column.
__global__ void k2b_tfrag(const float* __restrict__ kc, unsigned short* __restrict__ Tf) {
  const int cu = blockIdx.x;          // c*63+u
  const float* kcr = kc + cu * 64;
  const int t = threadIdx.x;
  #pragma unroll
  for (int s = 0; s < 2; ++s) {
    const int slot = t + s * 256;     // 0..511
    const int f = slot >> 6, lane = slot & 63;
    const int kt = f >> 1, nt = f & 1;
    const int kbase = kt * 16 + (lane >> 5) * 8;
    const int n = nt * 32 + (lane & 31);
    unsigned int o[4];
    #pragma unroll
    for (int jp = 0; jp < 4; ++jp) {
      unsigned short h0, h1;
      {
        const int v = (kbase + 2 * jp) - n + 31;
        h0 = (v >= 0 && v < 63) ? f2bf(kcr[v]) : 0;
      }
      {
        const int v = (kbase + 2 * jp + 1) - n + 31;
        h1 = (v >= 0 && v < 63) ? f2bf(kcr[v]) : 0;
      }
      o[jp] = (unsigned int)h0 | ((unsigned int)h1 << 16);
    }
    unsigned int* dst = (unsigned int*)(Tf + (cu * 8 + f) * 512 + lane * 8);
    dst[0] = o[0]; dst[1] = o[1]; dst[2] = o[2]; dst[3] = o[3];
  }
}

// ---------------- K3: transpose x (b,p,q,c) -> bf16 padded [bc][p+31][q] ----------------
// 128 blocks; pad-zeroing spread evenly over all blocks (3968 uints each).
__global__ void k3_xt(const float* __restrict__ x, unsigned short* __restrict__ Xpad) {
  __shared__ float ls[4 * 64 * 33];
  const int b = blockIdx.x >> 4, pt = blockIdx.x & 15;
  const int t = threadIdx.x;
  const float* src = x + (b * 64 + pt * 4) * 2048;
  #pragma unroll 8
  for (int k = 0; k < 32; ++k) {
    const int e = t + k * 256;                        // 0..8191
    const int p = e >> 11, q = (e >> 5) & 63, cl = e & 31;
    ls[(p * 64 + q) * 33 + cl] = src[e];
  }
  // pad rows: 512 segs of 992 uints (b,c,top/bot); total 507904, 3968/block
  unsigned int* Xp32 = (unsigned int*)Xpad;
  for (int idx = blockIdx.x * 3968 + t; idx < (blockIdx.x + 1) * 3968; idx += 256) {
    const int seg = idx / 992, off = idx - seg * 992;
    const int bb = seg >> 6, cc = (seg >> 1) & 31, hf = seg & 1;
    Xp32[(bb * 32 + cc) * 4032 + (hf ? 3040 : 0) + off] = 0u;
  }
  __syncthreads();
  #pragma unroll 8
  for (int k = 0; k < 16; ++k) {
    const int o = t + k * 256;                        // 0..4095 q-pairs
    const int cl = o >> 7, p = (o >> 5) & 3, q2 = o & 31;
    const float f0 = ls[(p * 64 + 2 * q2 + 0) * 33 + cl];
    const float f1 = ls[(p * 64 + 2 * q2 + 1) * 33 + cl];
    const unsigned int pk = (unsigned int)f2bf(f0) | ((unsigned int)f2bf(f1) << 16);
    Xp32[(b * 32 + cl) * 4032 + (pt * 4 + p + 31) * 32 + q2] = pk;
  }
}

// ---------------- K4b: conv as sum of 63 Toeplitz GEMMs (MFMA bf16) ----------------
__global__ __launch_bounds__(256, 2) void k4b_conv(const unsigned short* __restrict__ Xpad,
                                                   const unsigned short* __restrict__ Tf,
                                                   float* __restrict__ yc) {
  __shared__ float red[4 * 4096];
  const int bc = blockIdx.x;
  const int c  = bc & 31;
  const int t = threadIdx.x, w = t >> 6, lane = t & 63;
  const unsigned short* Xp = Xpad + bc * 8064;
  const unsigned short* Tc = Tf + c * 63 * 4096;
  const int r = lane & 31, kh = lane >> 5;

  f32x16 acc[2][2];
  #pragma unroll
  for (int m = 0; m < 2; ++m)
    #pragma unroll
    for (int n = 0; n < 2; ++n)
      #pragma unroll
      for (int e = 0; e < 16; ++e) acc[m][n][e] = 0.f;

  short8 Ac[2][4], Bc[4][2];
  int u = w;
  #pragma unroll
  for (int m = 0; m < 2; ++m)
    #pragma unroll
    for (int kt = 0; kt < 4; ++kt)
      Ac[m][kt] = *(const short8*)(Xp + (m * 32 + r + u) * 64 + kt * 16 + kh * 8);
  #pragma unroll
  for (int kt = 0; kt < 4; ++kt)
    #pragma unroll
    for (int nt = 0; nt < 2; ++nt)
      Bc[kt][nt] = *(const short8*)(Tc + (u * 8 + kt * 2 + nt) * 512 + lane * 8);

  for (int i = 0; i < 16; ++i) {
    const int un = u + 4;
    const bool has_next = (un < 63);
    short8 An[2][4], Bn[4][2];
    if (has_next) {
      #pragma unroll
      for (int m = 0; m < 2; ++m)
        #pragma unroll
        for (int kt = 0; kt < 4; ++kt)
          An[m][kt] = *(const short8*)(Xp + (m * 32 + r + un) * 64 + kt * 16 + kh * 8);
      #pragma unroll
      for (int kt = 0; kt < 4; ++kt)
        #pragma unroll
        for (int nt = 0; nt < 2; ++nt)
          Bn[kt][nt] = *(const short8*)(Tc + (un * 8 + kt * 2 + nt) * 512 + lane * 8);
    }
    #pragma unroll
    for (int kt = 0; kt < 4; ++kt)
      #pragma unroll
      for (int m = 0; m < 2; ++m)
        #pragma unroll
        for (int nt = 0; nt < 2; ++nt)
          acc[m][nt] = __builtin_amdgcn_mfma_f32_32x32x16_bf16(Ac[m][kt], Bc[kt][nt],
                                                               acc[m][nt], 0, 0, 0);
    if (!has_next) break;
    #pragma unroll
    for (int m = 0; m < 2; ++m)
      #pragma unroll
      for (int kt = 0; kt < 4; ++kt) Ac[m][kt] = An[m][kt];
    #pragma unroll
    for (int kt = 0; kt < 4; ++kt)
      #pragma unroll
      for (int nt = 0; nt < 2; ++nt) Bc[kt][nt] = Bn[kt][nt];
    u = un;
  }

  float* my = red + w * 4096;
  #pragma unroll
  for (int m = 0; m < 2; ++m)
    #pragma unroll
    for (int nt = 0; nt < 2; ++nt)
      #pragma unroll
      for (int e = 0; e < 16; ++e) {
        const int row = (e & 3) + 8 * (e >> 2) + 4 * kh;
        my[(m * 32 + row) * 64 + nt * 32 + r] = acc[m][nt][e];
      }
  __syncthreads();
  float* out = yc + bc * 4096;
  #pragma unroll
  for (int k = 0; k < 16; ++k) {
    const int idx = t + k * 256;
    out[idx] = red[idx] + red[4096 + idx] + red[8192 + idx] + red[12288 + idx];
  }
}

// ---------------- K5: channel mix y @ W^T + b ----------------
__global__ void k5_out(const float* __restrict__ yc, const float* __restrict__ W,
                       const float* __restrict__ bias, float* __restrict__ out) {
  __shared__ float ysh[64 * 33];
  const int b = blockIdx.x >> 6, p = blockIdx.x & 63;
  const int t = threadIdx.x;
  const float* ybp = yc + b * 131072 + p * 64;
  #pragma unroll
  for (int k = 0; k < 8; ++k) {
    const int f = t + k * 256;
    const int cch = f >> 6, q = f & 63;
    ysh[q * 33 + cch] = ybp[cch * 4096 + q];
  }
  const int e = t & 31;
  float wr[32];
  #pragma unroll
  for (int c4 = 0; c4 < 8; ++c4) {
    const float4 f4 = *(const float4*)(W + e * 32 + c4 * 4);
    wr[c4 * 4 + 0] = f4.x; wr[c4 * 4 + 1] = f4.y;
    wr[c4 * 4 + 2] = f4.z; wr[c4 * 4 + 3] = f4.w;
  }
  const float bb = bias[e];
  __syncthreads();
  const int q0 = t >> 5;
  #pragma unroll
  for (int k = 0; k < 8; ++k) {
    const int q = q0 + k * 8;
    float a = bb;
    #pragma unroll
    for (int cc = 0; cc < 32; ++cc) a = fmaf(ysh[q * 33 + cc], wr[cc], a);
    out[((b * 64 + p) * 64 + q) * 32 + e] = a;
  }
}

extern "C" void kernel_launch(void* const* d_in, const int* in_sizes, int n_in,
                              void* d_out, int out_size, void* d_ws, size_t ws_size,
                              hipStream_t stream) {
  const float* x   = (const float*)d_in[0];
  const float* Mh[5] = {(const float*)d_in[1], (const float*)d_in[2], (const float*)d_in[3],
                        (const float*)d_in[4], (const float*)d_in[5]};
  const float* Mv[5] = {(const float*)d_in[6], (const float*)d_in[7], (const float*)d_in[8],
                        (const float*)d_in[9], (const float*)d_in[10]};
  const float* A1 = (const float*)d_in[11];
  const float* A2 = (const float*)d_in[12];
  const float* A3 = (const float*)d_in[13];
  const float* A4 = (const float*)d_in[14];
  const float* B1 = (const float*)d_in[15];
  const float* B2 = (const float*)d_in[16];
  const float* C1 = (const float*)d_in[17];
  const float* C2 = (const float*)d_in[18];
  const float* W  = (const float*)d_in[19];
  const float* bb = (const float*)d_in[20];
  float* ws  = (float*)d_ws;
  _Float16* Bfh = (_Float16*)(ws + WS_BFH);
  float* bsg  = ws + WS_BSG;
  float* outs = ws + WS_OUTS;
  float* kc   = ws + WS_KC;
  unsigned short* Xpad = (unsigned short*)(ws + WS_XPAD);
  float* yc   = ws + WS_YC;
  unsigned short* Tf = (unsigned short*)(ws + WS_TF);

  k0_prep<<<8, 256, 0, stream>>>(A1, A2, A3, A4, B1, B2, Bfh, bsg);
  k3_xt<<<128, 256, 0, stream>>>(x, Xpad);
  k1_mfma<<<2048, 256, 0, stream>>>(Mh[0], Mh[1], Mh[2], Mh[3], Mh[4],
                                    Mv[0], Mv[1], Mv[2], Mv[3], Mv[4],
                                    Bfh, bsg, outs);
  k2_kc<<<256, 256, 0, stream>>>(outs, C1, C2, kc);
  k2b_tfrag<<<2016, 256, 0, stream>>>(kc, Tf);
  k4b_conv<<<256, 256, 0, stream>>>(Xpad, Tf, yc);
  k5_out<<<512, 256, 0, stream>>>(yc, W, bb, (float*)d_out);
}